// Round 1
// baseline (1048.025 us; speedup 1.0000x reference)
//
#include <hip/hip_runtime.h>
#include <hip/hip_bf16.h>
#include <math.h>

#define NN 100000
#define EE 1600000

// ---------------- fill ----------------
__global__ void k_fill4(float4* __restrict__ p, long n4, float v) {
    long i = (long)blockIdx.x * blockDim.x + threadIdx.x;
    if (i < n4) { float4 f = {v, v, v, v}; p[i] = f; }
}

// ---------------- edge weight: ew = sigmoid(emb_cat @ Wv^T + bv) ----------------
// 32 lanes per edge; lane l loads float4 at emb_cat[e*128 + l*4]
__global__ __launch_bounds__(256) void k_edge_ew(
    const float* __restrict__ emb, const float* __restrict__ Wv, const float* __restrict__ bv,
    const int* __restrict__ dst, float* __restrict__ ew, float* __restrict__ out_ew,
    float* __restrict__ deg, int E)
{
    int e = blockIdx.x * 8 + (threadIdx.x >> 5);
    if (e >= E) return;
    int l = threadIdx.x & 31;
    const float4 v = ((const float4*)(emb + (size_t)e * 128))[l];
    const float4 w = ((const float4*)Wv)[l];
    float dot = v.x * w.x + v.y * w.y + v.z * w.z + v.w * w.w;
#pragma unroll
    for (int m = 16; m >= 1; m >>= 1) dot += __shfl_xor(dot, m);
    if (l == 0) {
        float x = dot + bv[0];
        float s = 1.0f / (1.0f + expf(-x));
        ew[e] = s;
        out_ew[e] = 1.0f - s;
        atomicAdd(&deg[dst[e]], s);
    }
}

// ---------------- dis = rsqrt(deg) ----------------
__global__ void k_dis(const float* __restrict__ deg, float* __restrict__ dis, int n) {
    int i = blockIdx.x * blockDim.x + threadIdx.x;
    if (i < n) dis[i] = rsqrtf(deg[i]);   // deg >= 1 always (self loop)
}

// ---------------- Y[n][j] = sum_k X[n][k] * W[j][k]  (X: n x 64, W: 64x64) ----------------
__global__ __launch_bounds__(256) void k_gemm64(
    const float* __restrict__ X, const float* __restrict__ W, float* __restrict__ Y, int n)
{
    __shared__ float w[64][64];
    for (int i = threadIdx.x; i < 64 * 64; i += 256) w[i >> 6][i & 63] = W[i];
    __syncthreads();
    int node = blockIdx.x * 256 + threadIdx.x;
    if (node >= n) return;
    float r[64];
    const float4* xr = (const float4*)(X + (size_t)node * 64);
#pragma unroll
    for (int q = 0; q < 16; ++q) {
        float4 v = xr[q];
        r[4 * q] = v.x; r[4 * q + 1] = v.y; r[4 * q + 2] = v.z; r[4 * q + 3] = v.w;
    }
    float4* yr = (float4*)(Y + (size_t)node * 64);
    for (int j = 0; j < 64; j += 4) {
        float a0 = 0.f, a1 = 0.f, a2 = 0.f, a3 = 0.f;
#pragma unroll
        for (int k = 0; k < 64; ++k) {
            a0 += r[k] * w[j][k];
            a1 += r[k] * w[j + 1][k];
            a2 += r[k] * w[j + 2][k];
            a3 += r[k] * w[j + 3][k];
        }
        float4 acc = {a0, a1, a2, a3};
        yr[j >> 2] = acc;
    }
}

// ---------------- scatter aggregation: B[dst] += dis[s]*ew*dis[d] * A[src] ----------------
__global__ __launch_bounds__(256) void k_agg(
    const float* __restrict__ A, float* __restrict__ B,
    const int* __restrict__ src, const int* __restrict__ dst,
    const float* __restrict__ ew, const float* __restrict__ dis, int E)
{
    int e = blockIdx.x * 4 + (threadIdx.x >> 6);
    if (e >= E) return;
    int lane = threadIdx.x & 63;
    int s = src[e], d = dst[e];
    float c = dis[s] * ew[e] * dis[d];
    atomicAdd(&B[(size_t)d * 64 + lane], c * A[(size_t)s * 64 + lane]);
}

// ---------------- layer-1 epilogue: B = relu(B + dis^2 * A + b1) ----------------
__global__ void k_post1(const float* __restrict__ A, float* __restrict__ B,
                        const float* __restrict__ dis, const float* __restrict__ b1, int n)
{
    int idx = blockIdx.x * blockDim.x + threadIdx.x;
    if (idx >= n * 64) return;
    int i = idx >> 6, k = idx & 63;
    float ds = dis[i];
    float v = B[idx] + ds * ds * A[idx] + b1[k];
    B[idx] = fmaxf(v, 0.0f);
}

// ---------------- final: h2 = B + dis^2*A + b2; logits = [h2, label]@Wc^T + bc; softmax ----------------
__global__ __launch_bounds__(256) void k_final(
    const float* __restrict__ B, const float* __restrict__ A, const float* __restrict__ dis,
    const float* __restrict__ b2, const float* __restrict__ labels,
    const float* __restrict__ Wc, const float* __restrict__ bc,
    float* __restrict__ out, int n)
{
    int i = blockIdx.x * 4 + (threadIdx.x >> 6);
    if (i >= n) return;
    int k = threadIdx.x & 63;
    size_t idx = (size_t)i * 64 + k;
    float ds = dis[i];
    float h = B[idx] + ds * ds * A[idx] + b2[k];
    float p0 = h * Wc[k];        // Wc row 0 (65 wide)
    float p1 = h * Wc[65 + k];   // Wc row 1
#pragma unroll
    for (int m = 1; m < 64; m <<= 1) {
        p0 += __shfl_xor(p0, m);
        p1 += __shfl_xor(p1, m);
    }
    if (k == 0) {
        float lab = labels[i];
        float l0 = p0 + lab * Wc[64] + bc[0];
        float l1 = p1 + lab * Wc[65 + 64] + bc[1];
        float mx = fmaxf(l0, l1);
        float e0 = expf(l0 - mx), e1 = expf(l1 - mx);
        float inv = 1.0f / (e0 + e1);
        out[2 * (size_t)i] = e0 * inv;
        out[2 * (size_t)i + 1] = e1 * inv;
    }
}

extern "C" void kernel_launch(void* const* d_in, const int* in_sizes, int n_in,
                              void* d_out, int out_size, void* d_ws, size_t ws_size,
                              hipStream_t stream)
{
    const float* emb      = (const float*)d_in[0];
    const float* features = (const float*)d_in[1];
    const float* labels   = (const float*)d_in[2];
    const float* Wv       = (const float*)d_in[3];
    const float* bv       = (const float*)d_in[4];
    const float* W1       = (const float*)d_in[5];
    const float* b1       = (const float*)d_in[6];
    const float* W2       = (const float*)d_in[7];
    const float* b2       = (const float*)d_in[8];
    const float* Wc       = (const float*)d_in[9];
    const float* bc       = (const float*)d_in[10];
    const int*   eidx     = (const int*)d_in[11];

    const int E = in_sizes[11] / 2;   // 1600000
    const int N = in_sizes[1] / 64;   // 100000
    const int* src = eidx;
    const int* dst = eidx + E;

    float* out       = (float*)d_out;
    float* out_sens  = out;                     // N*2
    float* out_ew    = out + 2 * (size_t)N;     // E

    // workspace layout (floats): ew[E] | deg[N] | dis[N] | A[N*64] | B[N*64]
    float* ew  = (float*)d_ws;
    float* deg = ew + E;
    float* dis = deg + N;
    float* A   = dis + N;
    float* B   = A + (size_t)N * 64;

    // deg = 1.0 (self loop), B = 0
    k_fill4<<<(N / 4 + 255) / 256, 256, 0, stream>>>((float4*)deg, N / 4, 1.0f);
    k_fill4<<<((size_t)N * 16 + 255) / 256, 256, 0, stream>>>((float4*)B, (size_t)N * 16, 0.0f);

    // edge weights + weighted in-degree
    k_edge_ew<<<(E + 7) / 8, 256, 0, stream>>>(emb, Wv, bv, dst, ew, out_ew, deg, E);
    k_dis<<<(N + 255) / 256, 256, 0, stream>>>(deg, dis, N);

    // layer 1
    k_gemm64<<<(N + 255) / 256, 256, 0, stream>>>(features, W1, A, N);
    k_agg<<<(E + 3) / 4, 256, 0, stream>>>(A, B, src, dst, ew, dis, E);
    k_post1<<<((size_t)N * 64 + 255) / 256, 256, 0, stream>>>(A, B, dis, b1, N);

    // layer 2: x2 = h @ W2^T  (h is in B, x2 -> A)
    k_gemm64<<<(N + 255) / 256, 256, 0, stream>>>(B, W2, A, N);
    k_fill4<<<((size_t)N * 16 + 255) / 256, 256, 0, stream>>>((float4*)B, (size_t)N * 16, 0.0f);
    k_agg<<<(E + 3) / 4, 256, 0, stream>>>(A, B, src, dst, ew, dis, E);

    // classifier + softmax
    k_final<<<(N + 3) / 4, 256, 0, stream>>>(B, A, dis, b2, labels, Wc, bc, out_sens, N);
}

// Round 2
// 644.986 us; speedup vs baseline: 1.6249x; 1.6249x over previous
//
#include <hip/hip_runtime.h>
#include <hip/hip_bf16.h>
#include <math.h>

// ---------------- fills ----------------
__global__ void k_fillf(float* __restrict__ p, int n, float v) {
    int i = blockIdx.x * blockDim.x + threadIdx.x;
    if (i < n) p[i] = v;
}
__global__ void k_filli(int* __restrict__ p, int n, int v) {
    int i = blockIdx.x * blockDim.x + threadIdx.x;
    if (i < n) p[i] = v;
}

// ---------------- edge weight: ew = sigmoid(emb_cat @ Wv^T + bv) ----------------
// 32 lanes per edge; lane l loads float4 at emb_cat[e*128 + l*4].
// Lane 0 also bumps weighted degree and integer in-degree count.
__global__ __launch_bounds__(256) void k_edge_ew(
    const float* __restrict__ emb, const float* __restrict__ Wv, const float* __restrict__ bv,
    const int* __restrict__ dst, float* __restrict__ ew, float* __restrict__ out_ew,
    float* __restrict__ deg, int* __restrict__ cnt, int E)
{
    int e = blockIdx.x * 8 + (threadIdx.x >> 5);
    if (e >= E) return;
    int l = threadIdx.x & 31;
    const float4 v = ((const float4*)(emb + (size_t)e * 128))[l];
    const float4 w = ((const float4*)Wv)[l];
    float dot = v.x * w.x + v.y * w.y + v.z * w.z + v.w * w.w;
#pragma unroll
    for (int m = 16; m >= 1; m >>= 1) dot += __shfl_xor(dot, m);
    if (l == 0) {
        float x = dot + bv[0];
        float s = 1.0f / (1.0f + expf(-x));
        ew[e] = s;
        out_ew[e] = 1.0f - s;
        int d = dst[e];
        atomicAdd(&deg[d], s);
        atomicAdd(&cnt[d], 1);
    }
}

// ---------------- dis = rsqrt(deg) ----------------
__global__ void k_dis(const float* __restrict__ deg, float* __restrict__ dis, int n) {
    int i = blockIdx.x * blockDim.x + threadIdx.x;
    if (i < n) dis[i] = rsqrtf(deg[i]);   // deg >= 1 (self loop)
}

// ---------------- scan phase 1: per-block (1024 elems) sums ----------------
__global__ __launch_bounds__(256) void k_scan_bsum(const int* __restrict__ cnt, int* __restrict__ bsum, int N) {
    int b = blockIdx.x, t = threadIdx.x;
    int base = b * 1024;
    int s = 0;
#pragma unroll
    for (int q = 0; q < 4; ++q) { int i = base + t * 4 + q; if (i < N) s += cnt[i]; }
    __shared__ int red[256];
    red[t] = s; __syncthreads();
    for (int off = 128; off > 0; off >>= 1) { if (t < off) red[t] += red[t + off]; __syncthreads(); }
    if (t == 0) bsum[b] = red[0];
}

// ---------------- scan phase 2: exclusive scan of <=128 block sums ----------------
__global__ __launch_bounds__(128) void k_scan_top(const int* __restrict__ bsum, int* __restrict__ boff, int nb) {
    __shared__ int a[128], b2[128];
    int t = threadIdx.x;
    int v = (t < nb) ? bsum[t] : 0;
    a[t] = v; __syncthreads();
    int* cur = a; int* nxt = b2;
    for (int off = 1; off < 128; off <<= 1) {
        int x = cur[t];
        if (t >= off) x += cur[t - off];
        nxt[t] = x; __syncthreads();
        int* tmp = cur; cur = nxt; nxt = tmp;
    }
    if (t < nb) boff[t] = cur[t] - v;   // exclusive
}

// ---------------- scan phase 3: write rowptr + cursor ----------------
__global__ __launch_bounds__(256) void k_scan_write(const int* __restrict__ cnt, const int* __restrict__ boff,
                                                    int* __restrict__ rowptr, int* __restrict__ cursor, int N) {
    int b = blockIdx.x, t = threadIdx.x;
    int base = b * 1024;
    int v[4]; int s = 0;
#pragma unroll
    for (int q = 0; q < 4; ++q) { int i = base + t * 4 + q; v[q] = (i < N) ? cnt[i] : 0; s += v[q]; }
    __shared__ int a[256], b2[256];
    a[t] = s; __syncthreads();
    int* cur = a; int* nxt = b2;
    for (int off = 1; off < 256; off <<= 1) {
        int x = cur[t];
        if (t >= off) x += cur[t - off];
        nxt[t] = x; __syncthreads();
        int* tmp = cur; cur = nxt; nxt = tmp;
    }
    int excl = cur[t] - s + boff[b];
#pragma unroll
    for (int q = 0; q < 4; ++q) {
        int i = base + t * 4 + q;
        if (i < N) { rowptr[i] = excl; cursor[i] = excl; excl += v[q]; }
    }
}

// ---------------- placement: dst-sorted (src, coef) lists ----------------
__global__ __launch_bounds__(256) void k_place(const int* __restrict__ src, const int* __restrict__ dst,
                                               const float* __restrict__ ew, const float* __restrict__ dis,
                                               int* __restrict__ cursor, int* __restrict__ ssrc,
                                               float* __restrict__ coef, int E) {
    int e = blockIdx.x * 256 + threadIdx.x;
    if (e >= E) return;
    int s = src[e], d = dst[e];
    int p = atomicAdd(&cursor[d], 1);
    ssrc[p] = s;
    coef[p] = dis[s] * ew[e] * dis[d];
}

// ---------------- Y[n][j] = sum_k X[n][k] * W[j][k] ----------------
__global__ __launch_bounds__(256) void k_gemm64(
    const float* __restrict__ X, const float* __restrict__ W, float* __restrict__ Y, int n)
{
    __shared__ float w[64][64];
    for (int i = threadIdx.x; i < 64 * 64; i += 256) w[i >> 6][i & 63] = W[i];
    __syncthreads();
    int node = blockIdx.x * 256 + threadIdx.x;
    if (node >= n) return;
    float r[64];
    const float4* xr = (const float4*)(X + (size_t)node * 64);
#pragma unroll
    for (int q = 0; q < 16; ++q) {
        float4 v = xr[q];
        r[4 * q] = v.x; r[4 * q + 1] = v.y; r[4 * q + 2] = v.z; r[4 * q + 3] = v.w;
    }
    float4* yr = (float4*)(Y + (size_t)node * 64);
    for (int j = 0; j < 64; j += 4) {
        float a0 = 0.f, a1 = 0.f, a2 = 0.f, a3 = 0.f;
#pragma unroll
        for (int k = 0; k < 64; ++k) {
            a0 += r[k] * w[j][k];
            a1 += r[k] * w[j + 1][k];
            a2 += r[k] * w[j + 2][k];
            a3 += r[k] * w[j + 3][k];
        }
        float4 acc = {a0, a1, a2, a3};
        yr[j >> 2] = acc;
    }
}

// ---------------- layer-1 gather-aggregate + self-loop + bias + ReLU ----------------
// one wave per node; lane = feature
__global__ __launch_bounds__(256) void k_agg1(
    const float* __restrict__ A, const int* __restrict__ rowptr, const int* __restrict__ cnt,
    const int* __restrict__ ssrc, const float* __restrict__ coef, const float* __restrict__ dis,
    const float* __restrict__ b1, float* __restrict__ H, int N)
{
    int node = blockIdx.x * 4 + (threadIdx.x >> 6);
    if (node >= N) return;
    int lane = threadIdx.x & 63;
    int rp = rowptr[node], c = cnt[node];
    float acc = 0.f;
    for (int jb = 0; jb < c; jb += 64) {
        int m = min(64, c - jb);
        int sv = 0; float cv = 0.f;
        if (lane < m) { sv = ssrc[rp + jb + lane]; cv = coef[rp + jb + lane]; }
        for (int j = 0; j < m; ++j) {
            int s = __shfl(sv, j);
            float w = __shfl(cv, j);
            acc += w * A[(size_t)s * 64 + lane];
        }
    }
    float ds = dis[node];
    float h = acc + ds * ds * A[(size_t)node * 64 + lane] + b1[lane];
    H[(size_t)node * 64 + lane] = fmaxf(h, 0.f);
}

// ---------------- layer-2 gather-aggregate fused with classifier + softmax ----------------
__global__ __launch_bounds__(256) void k_agg2_final(
    const float* __restrict__ A, const int* __restrict__ rowptr, const int* __restrict__ cnt,
    const int* __restrict__ ssrc, const float* __restrict__ coef, const float* __restrict__ dis,
    const float* __restrict__ b2, const float* __restrict__ labels,
    const float* __restrict__ Wc, const float* __restrict__ bc,
    float* __restrict__ out, int N)
{
    int node = blockIdx.x * 4 + (threadIdx.x >> 6);
    if (node >= N) return;
    int lane = threadIdx.x & 63;
    int rp = rowptr[node], c = cnt[node];
    float acc = 0.f;
    for (int jb = 0; jb < c; jb += 64) {
        int m = min(64, c - jb);
        int sv = 0; float cv = 0.f;
        if (lane < m) { sv = ssrc[rp + jb + lane]; cv = coef[rp + jb + lane]; }
        for (int j = 0; j < m; ++j) {
            int s = __shfl(sv, j);
            float w = __shfl(cv, j);
            acc += w * A[(size_t)s * 64 + lane];
        }
    }
    float ds = dis[node];
    float h = acc + ds * ds * A[(size_t)node * 64 + lane] + b2[lane];
    float p0 = h * Wc[lane];        // Wc row 0 (width 65)
    float p1 = h * Wc[65 + lane];   // Wc row 1
#pragma unroll
    for (int mm = 1; mm < 64; mm <<= 1) {
        p0 += __shfl_xor(p0, mm);
        p1 += __shfl_xor(p1, mm);
    }
    if (lane == 0) {
        float lab = labels[node];
        float l0 = p0 + lab * Wc[64] + bc[0];
        float l1 = p1 + lab * Wc[65 + 64] + bc[1];
        float mx = fmaxf(l0, l1);
        float e0 = expf(l0 - mx), e1 = expf(l1 - mx);
        float inv = 1.0f / (e0 + e1);
        out[2 * (size_t)node]     = e0 * inv;
        out[2 * (size_t)node + 1] = e1 * inv;
    }
}

extern "C" void kernel_launch(void* const* d_in, const int* in_sizes, int n_in,
                              void* d_out, int out_size, void* d_ws, size_t ws_size,
                              hipStream_t stream)
{
    const float* emb      = (const float*)d_in[0];
    const float* features = (const float*)d_in[1];
    const float* labels   = (const float*)d_in[2];
    const float* Wv       = (const float*)d_in[3];
    const float* bv       = (const float*)d_in[4];
    const float* W1       = (const float*)d_in[5];
    const float* b1       = (const float*)d_in[6];
    const float* W2       = (const float*)d_in[7];
    const float* b2       = (const float*)d_in[8];
    const float* Wc       = (const float*)d_in[9];
    const float* bc       = (const float*)d_in[10];
    const int*   eidx     = (const int*)d_in[11];

    const int E = in_sizes[11] / 2;   // 1600000
    const int N = in_sizes[1] / 64;   // 100000
    const int* src = eidx;
    const int* dst = eidx + E;

    float* out      = (float*)d_out;
    float* out_sens = out;                  // N*2
    float* out_ew   = out + 2 * (size_t)N;  // E

    // workspace layout (4B elems):
    // ew[E] | deg[N] | dis[N] | A[N*64] | H[N*64] | cnt[N] | rowptr[N] | cursor[N]
    // | bsum[128] | boff[128] | ssrc[E] | coef[E]
    float* ew     = (float*)d_ws;
    float* deg    = ew + E;
    float* dis    = deg + N;
    float* A      = dis + N;
    float* H      = A + (size_t)N * 64;
    int*   cnt    = (int*)(H + (size_t)N * 64);
    int*   rowptr = cnt + N;
    int*   cursor = rowptr + N;
    int*   bsum   = cursor + N;
    int*   boff   = bsum + 128;
    int*   ssrc   = boff + 128;
    float* coef   = (float*)(ssrc + E);

    const int NB = (N + 1023) / 1024;   // scan blocks (98 <= 128)

    // init
    k_fillf<<<(N + 255) / 256, 256, 0, stream>>>(deg, N, 1.0f);   // self-loop weight
    k_filli<<<(N + 255) / 256, 256, 0, stream>>>(cnt, N, 0);

    // edge weights + weighted degree + in-degree counts
    k_edge_ew<<<(E + 7) / 8, 256, 0, stream>>>(emb, Wv, bv, dst, ew, out_ew, deg, cnt, E);
    k_dis<<<(N + 255) / 256, 256, 0, stream>>>(deg, dis, N);

    // CSR build (dst-sorted edge lists)
    k_scan_bsum<<<NB, 256, 0, stream>>>(cnt, bsum, N);
    k_scan_top<<<1, 128, 0, stream>>>(bsum, boff, NB);
    k_scan_write<<<NB, 256, 0, stream>>>(cnt, boff, rowptr, cursor, N);
    k_place<<<(E + 255) / 256, 256, 0, stream>>>(src, dst, ew, dis, cursor, ssrc, coef, E);

    // layer 1: A = X@W1^T ; H = relu(agg(A) + dis^2*A + b1)
    k_gemm64<<<(N + 255) / 256, 256, 0, stream>>>(features, W1, A, N);
    k_agg1<<<(N + 3) / 4, 256, 0, stream>>>(A, rowptr, cnt, ssrc, coef, dis, b1, H, N);

    // layer 2: A = H@W2^T ; fused agg + classifier + softmax
    k_gemm64<<<(N + 255) / 256, 256, 0, stream>>>(H, W2, A, N);
    k_agg2_final<<<(N + 3) / 4, 256, 0, stream>>>(A, rowptr, cnt, ssrc, coef, dis, b2,
                                                  labels, Wc, bc, out_sens, N);
}

// Round 3
// 549.742 us; speedup vs baseline: 1.9064x; 1.1733x over previous
//
#include <hip/hip_runtime.h>
#include <hip/hip_bf16.h>
#include <math.h>

typedef unsigned long long u64;

// ---------------- init: deg=1 (self loop), cnt=0 ----------------
__global__ void k_init(float* __restrict__ deg, int* __restrict__ cnt, int n) {
    int i = blockIdx.x * blockDim.x + threadIdx.x;
    if (i < n) { deg[i] = 1.0f; cnt[i] = 0; }
}

// ---------------- edge weight: ew = sigmoid(emb_cat @ Wv^T + bv) ----------------
__global__ __launch_bounds__(256) void k_edge_ew(
    const float* __restrict__ emb, const float* __restrict__ Wv, const float* __restrict__ bv,
    const int* __restrict__ dst, float* __restrict__ ew, float* __restrict__ out_ew,
    float* __restrict__ deg, int* __restrict__ cnt, int E)
{
    int e = blockIdx.x * 8 + (threadIdx.x >> 5);
    if (e >= E) return;
    int l = threadIdx.x & 31;
    const float4 v = ((const float4*)(emb + (size_t)e * 128))[l];
    const float4 w = ((const float4*)Wv)[l];
    float dot = v.x * w.x + v.y * w.y + v.z * w.z + v.w * w.w;
#pragma unroll
    for (int m = 16; m >= 1; m >>= 1) dot += __shfl_xor(dot, m);
    if (l == 0) {
        float x = dot + bv[0];
        float s = 1.0f / (1.0f + expf(-x));
        ew[e] = s;
        out_ew[e] = 1.0f - s;
        int d = dst[e];
        atomicAdd(&deg[d], s);
        atomicAdd(&cnt[d], 1);
    }
}

// ---------------- scan phase 1: per-block (1024 elems) sums; also dis=rsqrt(deg) ----------------
__global__ __launch_bounds__(256) void k_scan_bsum(const int* __restrict__ cnt, int* __restrict__ bsum,
                                                   const float* __restrict__ deg, float* __restrict__ dis, int N) {
    int b = blockIdx.x, t = threadIdx.x;
    int base = b * 1024;
    int s = 0;
#pragma unroll
    for (int q = 0; q < 4; ++q) {
        int i = base + t * 4 + q;
        if (i < N) { s += cnt[i]; dis[i] = rsqrtf(deg[i]); }
    }
    __shared__ int red[256];
    red[t] = s; __syncthreads();
    for (int off = 128; off > 0; off >>= 1) { if (t < off) red[t] += red[t + off]; __syncthreads(); }
    if (t == 0) bsum[b] = red[0];
}

// ---------------- scan phase 2: exclusive scan of <=128 block sums ----------------
__global__ __launch_bounds__(128) void k_scan_top(const int* __restrict__ bsum, int* __restrict__ boff, int nb) {
    __shared__ int a[128], b2[128];
    int t = threadIdx.x;
    int v = (t < nb) ? bsum[t] : 0;
    a[t] = v; __syncthreads();
    int* cur = a; int* nxt = b2;
    for (int off = 1; off < 128; off <<= 1) {
        int x = cur[t];
        if (t >= off) x += cur[t - off];
        nxt[t] = x; __syncthreads();
        int* tmp = cur; cur = nxt; nxt = tmp;
    }
    if (t < nb) boff[t] = cur[t] - v;   // exclusive
}

// ---------------- scan phase 3: write rowptr + cursor ----------------
__global__ __launch_bounds__(256) void k_scan_write(const int* __restrict__ cnt, const int* __restrict__ boff,
                                                    int* __restrict__ rowptr, int* __restrict__ cursor, int N) {
    int b = blockIdx.x, t = threadIdx.x;
    int base = b * 1024;
    int v[4]; int s = 0;
#pragma unroll
    for (int q = 0; q < 4; ++q) { int i = base + t * 4 + q; v[q] = (i < N) ? cnt[i] : 0; s += v[q]; }
    __shared__ int a[256], b2[256];
    a[t] = s; __syncthreads();
    int* cur = a; int* nxt = b2;
    for (int off = 1; off < 256; off <<= 1) {
        int x = cur[t];
        if (t >= off) x += cur[t - off];
        nxt[t] = x; __syncthreads();
        int* tmp = cur; cur = nxt; nxt = tmp;
    }
    int excl = cur[t] - s + boff[b];
#pragma unroll
    for (int q = 0; q < 4; ++q) {
        int i = base + t * 4 + q;
        if (i < N) { rowptr[i] = excl; cursor[i] = excl; excl += v[q]; }
    }
}

// ---------------- placement: dst-sorted packed (src, coef) records ----------------
__global__ __launch_bounds__(256) void k_place(const int* __restrict__ src, const int* __restrict__ dst,
                                               const float* __restrict__ ew, const float* __restrict__ dis,
                                               int* __restrict__ cursor, u64* __restrict__ edat, int E) {
    int e = blockIdx.x * 256 + threadIdx.x;
    if (e >= E) return;
    int s = src[e], d = dst[e];
    int p = atomicAdd(&cursor[d], 1);
    float c = dis[s] * ew[e] * dis[d];
    edat[p] = ((u64)__float_as_uint(c) << 32) | (unsigned)s;
}

// ---------------- Y[n][j] = sum_k X[n][k] * W[j][k] ----------------
__global__ __launch_bounds__(256) void k_gemm64(
    const float* __restrict__ X, const float* __restrict__ W, float* __restrict__ Y, int n)
{
    __shared__ float w[64][64];
    for (int i = threadIdx.x; i < 64 * 64; i += 256) w[i >> 6][i & 63] = W[i];
    __syncthreads();
    int node = blockIdx.x * 256 + threadIdx.x;
    if (node >= n) return;
    float r[64];
    const float4* xr = (const float4*)(X + (size_t)node * 64);
#pragma unroll
    for (int q = 0; q < 16; ++q) {
        float4 v = xr[q];
        r[4 * q] = v.x; r[4 * q + 1] = v.y; r[4 * q + 2] = v.z; r[4 * q + 3] = v.w;
    }
    float4* yr = (float4*)(Y + (size_t)node * 64);
    for (int j = 0; j < 64; j += 4) {
        float a0 = 0.f, a1 = 0.f, a2 = 0.f, a3 = 0.f;
#pragma unroll
        for (int k = 0; k < 64; ++k) {
            a0 += r[k] * w[j][k];
            a1 += r[k] * w[j + 1][k];
            a2 += r[k] * w[j + 2][k];
            a3 += r[k] * w[j + 3][k];
        }
        float4 acc = {a0, a1, a2, a3};
        yr[j >> 2] = acc;
    }
}

// ---------------- gather-aggregate core: 8-wide batched, branchless ----------------
// acc = sum over c edges of coef * A[src][lane]; pads load ed[cm1] with weight 0.
__device__ __forceinline__ float agg_node(const float* __restrict__ A, const u64* __restrict__ ed,
                                          int c, int lane)
{
    float acc = 0.f;
    int cm1 = (c > 0) ? c - 1 : 0;
    for (int j = 0; j < c; j += 8) {
        u64 e[8];
#pragma unroll
        for (int q = 0; q < 8; ++q) {
            int idx = j + q;
            e[q] = ed[min(idx, cm1)];           // always a valid address
        }
        float v[8];
#pragma unroll
        for (int q = 0; q < 8; ++q) {
            int s = (int)(unsigned)(e[q] & 0xffffffffu);
            v[q] = A[(size_t)s * 64 + lane];    // 8 independent gathers in flight
        }
#pragma unroll
        for (int q = 0; q < 8; ++q) {
            int idx = j + q;
            float w = (idx < c) ? __uint_as_float((unsigned)(e[q] >> 32)) : 0.f;
            acc += w * v[q];
        }
    }
    return acc;
}

// ---------------- layer-1 aggregate + self-loop + bias + ReLU ----------------
__global__ __launch_bounds__(256) void k_agg1(
    const float* __restrict__ A, const int* __restrict__ rowptr, const int* __restrict__ cnt,
    const u64* __restrict__ edat, const float* __restrict__ dis,
    const float* __restrict__ b1, float* __restrict__ H, int N)
{
    int node = blockIdx.x * 4 + (threadIdx.x >> 6);
    if (node >= N) return;
    int lane = threadIdx.x & 63;
    float acc = agg_node(A, edat + rowptr[node], cnt[node], lane);
    float ds = dis[node];
    float h = acc + ds * ds * A[(size_t)node * 64 + lane] + b1[lane];
    H[(size_t)node * 64 + lane] = fmaxf(h, 0.f);
}

// ---------------- layer-2 aggregate fused with classifier + softmax ----------------
__global__ __launch_bounds__(256) void k_agg2_final(
    const float* __restrict__ A, const int* __restrict__ rowptr, const int* __restrict__ cnt,
    const u64* __restrict__ edat, const float* __restrict__ dis,
    const float* __restrict__ b2, const float* __restrict__ labels,
    const float* __restrict__ Wc, const float* __restrict__ bc,
    float* __restrict__ out, int N)
{
    int node = blockIdx.x * 4 + (threadIdx.x >> 6);
    if (node >= N) return;
    int lane = threadIdx.x & 63;
    float acc = agg_node(A, edat + rowptr[node], cnt[node], lane);
    float ds = dis[node];
    float h = acc + ds * ds * A[(size_t)node * 64 + lane] + b2[lane];
    float p0 = h * Wc[lane];        // Wc row 0 (width 65)
    float p1 = h * Wc[65 + lane];   // Wc row 1
#pragma unroll
    for (int mm = 1; mm < 64; mm <<= 1) {
        p0 += __shfl_xor(p0, mm);
        p1 += __shfl_xor(p1, mm);
    }
    if (lane == 0) {
        float lab = labels[node];
        float l0 = p0 + lab * Wc[64] + bc[0];
        float l1 = p1 + lab * Wc[65 + 64] + bc[1];
        float mx = fmaxf(l0, l1);
        float e0 = expf(l0 - mx), e1 = expf(l1 - mx);
        float inv = 1.0f / (e0 + e1);
        out[2 * (size_t)node]     = e0 * inv;
        out[2 * (size_t)node + 1] = e1 * inv;
    }
}

extern "C" void kernel_launch(void* const* d_in, const int* in_sizes, int n_in,
                              void* d_out, int out_size, void* d_ws, size_t ws_size,
                              hipStream_t stream)
{
    const float* emb      = (const float*)d_in[0];
    const float* features = (const float*)d_in[1];
    const float* labels   = (const float*)d_in[2];
    const float* Wv       = (const float*)d_in[3];
    const float* bv       = (const float*)d_in[4];
    const float* W1       = (const float*)d_in[5];
    const float* b1       = (const float*)d_in[6];
    const float* W2       = (const float*)d_in[7];
    const float* b2       = (const float*)d_in[8];
    const float* Wc       = (const float*)d_in[9];
    const float* bc       = (const float*)d_in[10];
    const int*   eidx     = (const int*)d_in[11];

    const int E = in_sizes[11] / 2;   // 1600000
    const int N = in_sizes[1] / 64;   // 100000
    const int* src = eidx;
    const int* dst = eidx + E;

    float* out      = (float*)d_out;
    float* out_sens = out;                  // N*2
    float* out_ew   = out + 2 * (size_t)N;  // E

    // workspace layout (4B units, 8B-aligned where needed):
    // ew[E] | deg[N] | dis[N] | A[N*64] | H[N*64] | cnt[N] | rowptr[N] | cursor[N]
    // | bsum[128] | boff[128] | edat[(E+8) u64]
    float* ew     = (float*)d_ws;
    float* deg    = ew + E;
    float* dis    = deg + N;
    float* A      = dis + N;
    float* H      = A + (size_t)N * 64;
    int*   cnt    = (int*)(H + (size_t)N * 64);
    int*   rowptr = cnt + N;
    int*   cursor = rowptr + N;
    int*   bsum   = cursor + N;
    int*   boff   = bsum + 128;
    u64*   edat   = (u64*)(boff + 128);   // offset is even # of floats -> 8B aligned

    const int NB = (N + 1023) / 1024;   // 98 <= 128

    k_init<<<(N + 255) / 256, 256, 0, stream>>>(deg, cnt, N);
    k_edge_ew<<<(E + 7) / 8, 256, 0, stream>>>(emb, Wv, bv, dst, ew, out_ew, deg, cnt, E);

    // CSR build (dst-sorted) + dis
    k_scan_bsum<<<NB, 256, 0, stream>>>(cnt, bsum, deg, dis, N);
    k_scan_top<<<1, 128, 0, stream>>>(bsum, boff, NB);
    k_scan_write<<<NB, 256, 0, stream>>>(cnt, boff, rowptr, cursor, N);
    k_place<<<(E + 255) / 256, 256, 0, stream>>>(src, dst, ew, dis, cursor, edat, E);

    // layer 1
    k_gemm64<<<(N + 255) / 256, 256, 0, stream>>>(features, W1, A, N);
    k_agg1<<<(N + 3) / 4, 256, 0, stream>>>(A, rowptr, cnt, edat, dis, b1, H, N);

    // layer 2 + classifier + softmax
    k_gemm64<<<(N + 255) / 256, 256, 0, stream>>>(H, W2, A, N);
    k_agg2_final<<<(N + 3) / 4, 256, 0, stream>>>(A, rowptr, cnt, edat, dis, b2,
                                                  labels, Wc, bc, out_sens, N);
}